// Round 6
// baseline (104.463 us; speedup 1.0000x reference)
//
#include <hip/hip_runtime.h>
#include <math.h>

#define BB 4
#define LQ 2048
#define LK 2048
#define DK 512
#define DV 512

typedef __attribute__((ext_vector_type(8))) short bf16x8;
typedef __attribute__((ext_vector_type(4))) float f32x4;

// ws layout (f32-element offsets)
#define WS_QW    0                 // f32[8192]
#define WS_KW    8192              // f32[8192]
#define WS_M     16384             // f32[8192]
#define WS_INV   24576             // f32[8192]
#define WS_MPACK 32768             // u32[8192*64] = 2 MB
#define WS_V16   557056            // u16 vH[4194304], u16 vL[4194304] = 16.8 MB
#define WS_PART  4751360           // f32[2*4194304] = 33.6 MB
#define WS_NEEDED_SPLIT ((size_t)(WS_PART + 2 * 4194304) * 4)

__device__ inline void bsplit(float f, unsigned short& h, unsigned short& l) {
    unsigned int u  = __float_as_uint(f);
    unsigned int hu = u & 0xFFFF0000u;
    float rest = f - __uint_as_float(hu);
    h = (unsigned short)(u >> 16);
    l = (unsigned short)(__float_as_uint(rest) >> 16);
}

__device__ inline unsigned int packsplit(float f) {
    unsigned int u  = __float_as_uint(f);
    unsigned int hu = u & 0xFFFF0000u;
    float rest = f - __uint_as_float(hu);
    return hu | (__float_as_uint(rest) >> 16);
}

// ---------------------------------------------------------------------------
// A: qw/kw — one wave per row.
// ---------------------------------------------------------------------------
__global__ __launch_bounds__(256) void qkw_kernel(const float* __restrict__ q,
                                                  const float* __restrict__ k,
                                                  const float* __restrict__ w,
                                                  float* __restrict__ ws) {
    int gw   = (int)((blockIdx.x * blockDim.x + threadIdx.x) >> 6);
    int lane = threadIdx.x & 63;
    const int nq = BB * LQ;
    const float* row = (gw < nq) ? (q + (size_t)gw * DK) : (k + (size_t)(gw - nq) * DK);

    float acc = 0.f;
#pragma unroll
    for (int j = 0; j < DK; j += 256) {
        int idx = j + lane * 4;
        float4 rv = *reinterpret_cast<const float4*>(row + idx);
        float4 wv = *reinterpret_cast<const float4*>(w + idx);
        acc += rv.x * wv.x + rv.y * wv.y + rv.z * wv.z + rv.w * wv.w;
    }
#pragma unroll
    for (int off = 32; off >= 1; off >>= 1) acc += __shfl_xor(acc, off, 64);
    if (lane == 0) ws[gw] = acc;
}

// ---------------------------------------------------------------------------
// C: v -> MFMA-fragment-ordered split bf16 (hi/lo).
// vFrag u16 index: (((b*32 + n16)*64 + k32)*64 + lane)*8 + j
//   element = vT[n16*16 + (lane&15)][k32*32 + (lane>>4)*8 + j]
// ---------------------------------------------------------------------------
__global__ __launch_bounds__(256) void vpack_kernel(const float* __restrict__ v,
                                                    unsigned short* __restrict__ vH,
                                                    unsigned short* __restrict__ vL) {
    __shared__ unsigned int tile[32][517];
    const int k32 = blockIdx.x;
    const int b   = blockIdx.y;
    const int k0  = k32 * 32;
    const int t   = threadIdx.x;

#pragma unroll
    for (int i = 0; i < 16; ++i) {
        int flat = i * 256 + t;          // 0..4095
        int row  = flat >> 7;            // 0..31
        int c4   = flat & 127;           // float4 col
        float4 f = *reinterpret_cast<const float4*>(
            v + ((size_t)(b * LK + k0 + row)) * DV + c4 * 4);
        tile[row][c4 * 4 + 0] = packsplit(f.x);
        tile[row][c4 * 4 + 1] = packsplit(f.y);
        tile[row][c4 * 4 + 2] = packsplit(f.z);
        tile[row][c4 * 4 + 3] = packsplit(f.w);
    }
    __syncthreads();

    const int w = t >> 6, l = t & 63;
    const int rbase = (l >> 4) * 8;
#pragma unroll
    for (int f = 0; f < 8; ++f) {
        int n16 = w * 8 + f;
        int col = n16 * 16 + (l & 15);
        unsigned int pk[8];
#pragma unroll
        for (int j = 0; j < 8; ++j) pk[j] = tile[rbase + j][col];
        uint4 hiw, low;
        hiw.x = (pk[0] >> 16) | (pk[1] & 0xFFFF0000u);
        hiw.y = (pk[2] >> 16) | (pk[3] & 0xFFFF0000u);
        hiw.z = (pk[4] >> 16) | (pk[5] & 0xFFFF0000u);
        hiw.w = (pk[6] >> 16) | (pk[7] & 0xFFFF0000u);
        low.x = (pk[0] & 0xFFFFu) | (pk[1] << 16);
        low.y = (pk[2] & 0xFFFFu) | (pk[3] << 16);
        low.z = (pk[4] & 0xFFFFu) | (pk[5] << 16);
        low.w = (pk[6] & 0xFFFFu) | (pk[7] << 16);
        size_t u16base = (((size_t)(b * 32 + n16)) * 64 + k32) * 512;
        *reinterpret_cast<uint4*>(vH + u16base + l * 8) = hiw;
        *reinterpret_cast<uint4*>(vL + u16base + l * 8) = low;
    }
}

// ---------------------------------------------------------------------------
// B1: per-row masked softmax stats + bit-packed mask + full attn row write.
// One wave per row. Pass 1: max/sum (+pack mask bits, nibble per iter).
// Pass 2: recompute p exactly (f32) and write attn coalesced.
// ---------------------------------------------------------------------------
__global__ __launch_bounds__(256) void rowstat_kernel(const int* __restrict__ mask,
                                                      float* __restrict__ ws,
                                                      unsigned int* __restrict__ mpack,
                                                      float* __restrict__ attn) {
    __shared__ float kws[LK];
    const int b = (blockIdx.x * 4) / LQ;
    const int t = threadIdx.x;

    const float4* kw4 = reinterpret_cast<const float4*>(ws + WS_KW + b * LK);
#pragma unroll
    for (int i = 0; i < 2; ++i)
        reinterpret_cast<float4*>(kws)[t + i * 256] = kw4[t + i * 256];
    __syncthreads();

    const int wave = t >> 6, lane = t & 63;
    const int rid  = blockIdx.x * 4 + wave;
    const float qwv = ws[WS_QW + rid];
    const int* mrow = mask + (size_t)rid * LK;

    float m = -INFINITY, s = 0.f;
    unsigned int mybits = 0;   // nibble i = mask bits for k = (i*64+lane)*4 ..+3
#pragma unroll
    for (int i = 0; i < 8; ++i) {
        int e = (i * 64 + lane) * 4;
        int4  mi = *reinterpret_cast<const int4*>(mrow + e);
        float4 kv = reinterpret_cast<const float4*>(kws)[i * 64 + lane];
        float vals[4] = {kv.x, kv.y, kv.z, kv.w};
        int   msks[4] = {mi.x, mi.y, mi.z, mi.w};

        unsigned int bits = (msks[0] ? 1u : 0u) | (msks[1] ? 2u : 0u) |
                            (msks[2] ? 4u : 0u) | (msks[3] ? 8u : 0u);
        mybits |= bits << (i * 4);
        unsigned int wv = bits << ((lane & 7) * 4);
        wv |= __shfl_xor(wv, 1, 64);
        wv |= __shfl_xor(wv, 2, 64);
        wv |= __shfl_xor(wv, 4, 64);
        if ((lane & 7) == 0) mpack[(size_t)rid * 64 + i * 8 + (lane >> 3)] = wv;

#pragma unroll
        for (int j = 0; j < 4; ++j) {
            float sc = qwv - vals[j];
            sc = fmaxf(sc, 0.01f * sc);
            if (msks[j]) {
                if (sc > m) { s = s * __expf(m - sc) + 1.f; m = sc; }
                else        { s += __expf(sc - m); }
            }
        }
    }
#pragma unroll
    for (int off = 32; off >= 1; off >>= 1) {
        float mo = __shfl_xor(m, off, 64);
        float so = __shfl_xor(s, off, 64);
        float M  = fmaxf(m, mo);
        float sa = (m  == M) ? s  : s  * __expf(m  - M);
        float sb = (mo == M) ? so : so * __expf(mo - M);
        m = M; s = sa + sb;
    }
    const float inv = (s > 0.f) ? 1.f / s : 0.f;
    if (lane == 0) {
        ws[WS_M   + rid] = m;
        ws[WS_INV + rid] = inv;
    }

    // ---- pass 2: exact p, coalesced attn write ----
    float* arow = attn + (size_t)rid * LK;
#pragma unroll
    for (int i = 0; i < 8; ++i) {
        float4 kv = reinterpret_cast<const float4*>(kws)[i * 64 + lane];
        float vals[4] = {kv.x, kv.y, kv.z, kv.w};
        unsigned int bits = (mybits >> (i * 4)) & 0xFu;
        float p[4];
#pragma unroll
        for (int j = 0; j < 4; ++j) {
            float sc = qwv - vals[j];
            sc = fmaxf(sc, 0.01f * sc);
            p[j] = (bits & (1u << j)) ? __expf(sc - m) * inv : 0.f;
        }
        *reinterpret_cast<float4*>(arow + (i * 64 + lane) * 4) =
            make_float4(p[0], p[1], p[2], p[3]);
    }
}

// ---------------------------------------------------------------------------
// B2: p-compute (LDS only) + split-bf16 MFMA PV. No global stores in loop.
// M=64 q-tile, 512 thr (8 waves), wave = 64 q-rows x 64 n-cols.
// B-fragments software-pipelined (prefetch chunk s+1 during MFMA of s).
// ---------------------------------------------------------------------------
__global__ __launch_bounds__(512, 2) void pv_kernel(
        const unsigned int* __restrict__ mpack,
        const float* __restrict__ ws,
        const unsigned short* __restrict__ vH,
        const unsigned short* __restrict__ vL,
        float* __restrict__ dst,
        int nks) {
    __shared__ float kw_lds[2048];
    __shared__ unsigned int pH32[2048];
    __shared__ unsigned int pL32[2048];

    const int bid = blockIdx.x;
    const int ks  = (nks == 2) ? (bid & 1) : 0;
    const int rst = (nks == 2) ? (bid >> 1) : bid;
    const int b   = rst & 3;
    const int qt  = rst >> 2;              // 0..31
    const int kspan  = LK / nks;
    const int ksteps = kspan >> 5;
    const int kbase  = ks * kspan;
    float* dstk = dst + (size_t)ks * ((size_t)BB * LQ * DV);

    const int t = threadIdx.x;
    const int w = t >> 6, l = t & 63;

    // p-compute decode: thread t owns LDS u32 words t (rows 0..31) and t+512 (rows 32..63)
    const int m0   = t >> 8;               // 0..1
    const int lp   = (t >> 2) & 63;
    const int jp   = t & 3;
    const int row0 = m0 * 16 + (lp & 15);  // 0..31
    const int kk   = ((lp >> 4) << 3) + (jp << 1);   // even, 0..30
    const int rid0 = b * LQ + qt * 64 + row0;
    const int rid1 = rid0 + 32;

    const float qv0 = ws[WS_QW + rid0], mv0 = ws[WS_M + rid0], iv0 = ws[WS_INV + rid0];
    const float qv1 = ws[WS_QW + rid1], mv1 = ws[WS_M + rid1], iv1 = ws[WS_INV + rid1];
    const unsigned int* mrow0 = mpack + (size_t)rid0 * 64 + (kbase >> 5);
    const unsigned int* mrow1 = mpack + (size_t)rid1 * 64 + (kbase >> 5);

    // B fragment base offsets (u16 units) for chunk 0, per nb
    size_t nbase[4];
#pragma unroll
    for (int nb = 0; nb < 4; ++nb)
        nbase[nb] = (((size_t)(b * 32 + w * 4 + nb)) * 64 + (kbase >> 5)) * 512 + (size_t)l * 8;

    // prologue: load chunk-0 B-fragments
    bf16x8 bhC[4], blC[4], bhN[4], blN[4];
#pragma unroll
    for (int nb = 0; nb < 4; ++nb) {
        bhC[nb] = *reinterpret_cast<const bf16x8*>(vH + nbase[nb]);
        blC[nb] = *reinterpret_cast<const bf16x8*>(vL + nbase[nb]);
    }

    for (int i = t; i < kspan; i += 512)
        kw_lds[i] = ws[WS_KW + b * LK + kbase + i];

    f32x4 acc[4][4];
#pragma unroll
    for (int mf = 0; mf < 4; ++mf)
#pragma unroll
        for (int nb = 0; nb < 4; ++nb)
            acc[mf][nb] = (f32x4){0.f, 0.f, 0.f, 0.f};

    unsigned int mw0 = mrow0[0], mw1 = mrow1[0];
    unsigned int mw0N, mw1N;
    __syncthreads();

    for (int s = 0; s < ksteps; ++s) {
        // ---- phase 1: p-compute, LDS-only (no global stores!) ----
        float2 kw2 = *reinterpret_cast<const float2*>(&kw_lds[s * 32 + kk]);
        float sc00 = qv0 - kw2.x; sc00 = fmaxf(sc00, 0.01f * sc00);
        float sc01 = qv0 - kw2.y; sc01 = fmaxf(sc01, 0.01f * sc01);
        float sc10 = qv1 - kw2.x; sc10 = fmaxf(sc10, 0.01f * sc10);
        float sc11 = qv1 - kw2.y; sc11 = fmaxf(sc11, 0.01f * sc11);
        float p00 = ((mw0 >> kk) & 1u)       ? __expf(sc00 - mv0) * iv0 : 0.f;
        float p01 = ((mw0 >> (kk + 1)) & 1u) ? __expf(sc01 - mv0) * iv0 : 0.f;
        float p10 = ((mw1 >> kk) & 1u)       ? __expf(sc10 - mv1) * iv1 : 0.f;
        float p11 = ((mw1 >> (kk + 1)) & 1u) ? __expf(sc11 - mv1) * iv1 : 0.f;
        unsigned short h00, l00, h01, l01, h10, l10, h11, l11;
        bsplit(p00, h00, l00); bsplit(p01, h01, l01);
        bsplit(p10, h10, l10); bsplit(p11, h11, l11);
        pH32[t]       = (unsigned int)h00 | ((unsigned int)h01 << 16);
        pL32[t]       = (unsigned int)l00 | ((unsigned int)l01 << 16);
        pH32[t + 512] = (unsigned int)h10 | ((unsigned int)h11 << 16);
        pL32[t + 512] = (unsigned int)l10 | ((unsigned int)l11 << 16);
        __syncthreads();

        // ---- phase 2: prefetch chunk s+1 B + mask, then A-reads + 48 MFMAs ----
        const int sn = (s + 1 < ksteps) ? s + 1 : s;
        mw0N = mrow0[sn]; mw1N = mrow1[sn];
#pragma unroll
        for (int nb = 0; nb < 4; ++nb) {
            bhN[nb] = *reinterpret_cast<const bf16x8*>(vH + nbase[nb] + (size_t)sn * 512);
            blN[nb] = *reinterpret_cast<const bf16x8*>(vL + nbase[nb] + (size_t)sn * 512);
        }

        const bf16x8* pHf = reinterpret_cast<const bf16x8*>(pH32);
        const bf16x8* pLf = reinterpret_cast<const bf16x8*>(pL32);
        bf16x8 aH[4], aL[4];
#pragma unroll
        for (int mf = 0; mf < 4; ++mf) {
            aH[mf] = pHf[mf * 64 + l];
            aL[mf] = pLf[mf * 64 + l];
        }
#pragma unroll
        for (int nb = 0; nb < 4; ++nb)
#pragma unroll
            for (int mf = 0; mf < 4; ++mf) {
                acc[mf][nb] = __builtin_amdgcn_mfma_f32_16x16x32_bf16(aH[mf], bhC[nb], acc[mf][nb], 0, 0, 0);
                acc[mf][nb] = __builtin_amdgcn_mfma_f32_16x16x32_bf16(aH[mf], blC[nb], acc[mf][nb], 0, 0, 0);
                acc[mf][nb] = __builtin_amdgcn_mfma_f32_16x16x32_bf16(aL[mf], bhC[nb], acc[mf][nb], 0, 0, 0);
            }
        __syncthreads();

#pragma unroll
        for (int nb = 0; nb < 4; ++nb) { bhC[nb] = bhN[nb]; blC[nb] = blN[nb]; }
        mw0 = mw0N; mw1 = mw1N;
    }

    // ---- epilogue: C layout col = l&15, row = mf*16 + (l>>4)*4 + r ----
    float* obase = dstk + ((size_t)(b * LQ + qt * 64)) * DV + w * 64 + (l & 15);
#pragma unroll
    for (int mf = 0; mf < 4; ++mf)
#pragma unroll
        for (int nb = 0; nb < 4; ++nb)
#pragma unroll
            for (int r = 0; r < 4; ++r)
                obase[(size_t)(mf * 16 + (l >> 4) * 4 + r) * DV + nb * 16] = acc[mf][nb][r];
}

// ---------------------------------------------------------------------------
// Reduce: out = part0 + part1 (float4).
// ---------------------------------------------------------------------------
__global__ __launch_bounds__(256) void reduce_kernel(const float* __restrict__ p0,
                                                     const float* __restrict__ p1,
                                                     float* __restrict__ out) {
    const int n4 = BB * LQ * DV / 4;   // 1048576
    int i = blockIdx.x * 256 + threadIdx.x;
    const float4* a = reinterpret_cast<const float4*>(p0);
    const float4* c = reinterpret_cast<const float4*>(p1);
    float4* o = reinterpret_cast<float4*>(out);
    for (; i < n4; i += 262144) {
        float4 x = a[i], y = c[i];
        o[i] = make_float4(x.x + y.x, x.y + y.y, x.z + y.z, x.w + y.w);
    }
}

// ---------------------------------------------------------------------------
extern "C" void kernel_launch(void* const* d_in, const int* in_sizes, int n_in,
                              void* d_out, int out_size, void* d_ws, size_t ws_size,
                              hipStream_t stream) {
    const float* q    = (const float*)d_in[0];
    const float* k    = (const float*)d_in[1];
    const float* v    = (const float*)d_in[2];
    const int*   mask = (const int*)d_in[3];
    const float* w    = (const float*)d_in[4];

    float* out  = (float*)d_out;                       // [B, LQ, DV]
    float* attn = out + (size_t)BB * LQ * DV;          // [B, LQ, LK]
    float* ws   = (float*)d_ws;

    unsigned int*   mpack = (unsigned int*)(ws + WS_MPACK);
    unsigned short* vH    = (unsigned short*)(ws + WS_V16);
    unsigned short* vL    = vH + (size_t)BB * DV * LK;
    float* part0 = ws + WS_PART;
    float* part1 = part0 + (size_t)BB * LQ * DV;

    const bool split = ws_size >= WS_NEEDED_SPLIT;

    qkw_kernel<<<4096, 256, 0, stream>>>(q, k, w, ws);
    vpack_kernel<<<dim3(64, 4), 256, 0, stream>>>(v, vH, vL);
    rowstat_kernel<<<2048, 256, 0, stream>>>(mask, ws, mpack, attn);

    if (split) {
        // bid&7 = (ks, b) -> one (batch, k-half) v-slice per XCD (L2 locality)
        pv_kernel<<<256, 512, 0, stream>>>(mpack, ws, vH, vL, part0, 2);
        reduce_kernel<<<1024, 256, 0, stream>>>(part0, part1, out);
    } else {
        pv_kernel<<<128, 512, 0, stream>>>(mpack, ws, vH, vL, out, 1);
    }
}

// Round 7
// 94.895 us; speedup vs baseline: 1.1008x; 1.1008x over previous
//
#include <hip/hip_runtime.h>
#include <math.h>

#define BB 4
#define LQ 2048
#define LK 2048
#define DK 512
#define DV 512

typedef __attribute__((ext_vector_type(8))) short bf16x8;
typedef __attribute__((ext_vector_type(4))) float f32x4;

// ws layout (f32-element offsets)
#define WS_QW    0                 // f32[8192]
#define WS_KW    8192              // f32[8192]
#define WS_M     16384             // f32[8192]
#define WS_INV   24576             // f32[8192]
#define WS_V16   557056            // u16 vH[4194304], u16 vL[4194304] = 16.8 MB
#define WS_PART  4751360           // f32[2*4194304] = 33.6 MB
#define WS_NEEDED_SPLIT ((size_t)(WS_PART + 2 * 4194304) * 4)

__device__ inline void bsplit(float f, unsigned short& h, unsigned short& l) {
    unsigned int u  = __float_as_uint(f);
    unsigned int hu = u & 0xFFFF0000u;
    float rest = f - __uint_as_float(hu);
    h = (unsigned short)(u >> 16);
    l = (unsigned short)(__float_as_uint(rest) >> 16);
}

__device__ inline unsigned int packsplit(float f) {
    unsigned int u  = __float_as_uint(f);
    unsigned int hu = u & 0xFFFF0000u;
    float rest = f - __uint_as_float(hu);
    return hu | (__float_as_uint(rest) >> 16);
}

// ---------------------------------------------------------------------------
// A: qw/kw — one wave per row.
// ---------------------------------------------------------------------------
__global__ __launch_bounds__(256) void qkw_kernel(const float* __restrict__ q,
                                                  const float* __restrict__ k,
                                                  const float* __restrict__ w,
                                                  float* __restrict__ ws) {
    int gw   = (int)((blockIdx.x * blockDim.x + threadIdx.x) >> 6);
    int lane = threadIdx.x & 63;
    const int nq = BB * LQ;
    const float* row = (gw < nq) ? (q + (size_t)gw * DK) : (k + (size_t)(gw - nq) * DK);

    float acc = 0.f;
#pragma unroll
    for (int j = 0; j < DK; j += 256) {
        int idx = j + lane * 4;
        float4 rv = *reinterpret_cast<const float4*>(row + idx);
        float4 wv = *reinterpret_cast<const float4*>(w + idx);
        acc += rv.x * wv.x + rv.y * wv.y + rv.z * wv.z + rv.w * wv.w;
    }
#pragma unroll
    for (int off = 32; off >= 1; off >>= 1) acc += __shfl_xor(acc, off, 64);
    if (lane == 0) ws[gw] = acc;
}

// ---------------------------------------------------------------------------
// C: v -> MFMA-fragment-ordered split bf16 (hi/lo).
// vFrag u16 index: (((b*32 + n16)*64 + k32)*64 + lane)*8 + j
//   element = vT[n16*16 + (lane&15)][k32*32 + (lane>>4)*8 + j]
// ---------------------------------------------------------------------------
__global__ __launch_bounds__(256) void vpack_kernel(const float* __restrict__ v,
                                                    unsigned short* __restrict__ vH,
                                                    unsigned short* __restrict__ vL) {
    __shared__ unsigned int tile[32][517];
    const int k32 = blockIdx.x;
    const int b   = blockIdx.y;
    const int k0  = k32 * 32;
    const int t   = threadIdx.x;

#pragma unroll
    for (int i = 0; i < 16; ++i) {
        int flat = i * 256 + t;          // 0..4095
        int row  = flat >> 7;            // 0..31
        int c4   = flat & 127;           // float4 col
        float4 f = *reinterpret_cast<const float4*>(
            v + ((size_t)(b * LK + k0 + row)) * DV + c4 * 4);
        tile[row][c4 * 4 + 0] = packsplit(f.x);
        tile[row][c4 * 4 + 1] = packsplit(f.y);
        tile[row][c4 * 4 + 2] = packsplit(f.z);
        tile[row][c4 * 4 + 3] = packsplit(f.w);
    }
    __syncthreads();

    const int w = t >> 6, l = t & 63;
    const int rbase = (l >> 4) * 8;
#pragma unroll
    for (int f = 0; f < 8; ++f) {
        int n16 = w * 8 + f;
        int col = n16 * 16 + (l & 15);
        unsigned int pk[8];
#pragma unroll
        for (int j = 0; j < 8; ++j) pk[j] = tile[rbase + j][col];
        uint4 hiw, low;
        hiw.x = (pk[0] >> 16) | (pk[1] & 0xFFFF0000u);
        hiw.y = (pk[2] >> 16) | (pk[3] & 0xFFFF0000u);
        hiw.z = (pk[4] >> 16) | (pk[5] & 0xFFFF0000u);
        hiw.w = (pk[6] >> 16) | (pk[7] & 0xFFFF0000u);
        low.x = (pk[0] & 0xFFFFu) | (pk[1] << 16);
        low.y = (pk[2] & 0xFFFFu) | (pk[3] << 16);
        low.z = (pk[4] & 0xFFFFu) | (pk[5] << 16);
        low.w = (pk[6] & 0xFFFFu) | (pk[7] << 16);
        size_t u16base = (((size_t)(b * 32 + n16)) * 64 + k32) * 512;
        *reinterpret_cast<uint4*>(vH + u16base + l * 8) = hiw;
        *reinterpret_cast<uint4*>(vL + u16base + l * 8) = low;
    }
}

// ---------------------------------------------------------------------------
// B1: per-row masked softmax stats + full attn row write.
// Pass 1: max/sum (+keep mask bits in reg). Pass 2: exact p, coalesced write.
// ---------------------------------------------------------------------------
__global__ __launch_bounds__(256) void rowstat_kernel(const int* __restrict__ mask,
                                                      float* __restrict__ ws,
                                                      float* __restrict__ attn) {
    __shared__ float kws[LK];
    const int b = (blockIdx.x * 4) / LQ;
    const int t = threadIdx.x;

    const float4* kw4 = reinterpret_cast<const float4*>(ws + WS_KW + b * LK);
#pragma unroll
    for (int i = 0; i < 2; ++i)
        reinterpret_cast<float4*>(kws)[t + i * 256] = kw4[t + i * 256];
    __syncthreads();

    const int wave = t >> 6, lane = t & 63;
    const int rid  = blockIdx.x * 4 + wave;
    const float qwv = ws[WS_QW + rid];
    const int* mrow = mask + (size_t)rid * LK;

    float m = -INFINITY, s = 0.f;
    unsigned int mybits = 0;   // nibble i = mask bits for k = (i*64+lane)*4 ..+3
#pragma unroll
    for (int i = 0; i < 8; ++i) {
        int e = (i * 64 + lane) * 4;
        int4  mi = *reinterpret_cast<const int4*>(mrow + e);
        float4 kv = reinterpret_cast<const float4*>(kws)[i * 64 + lane];
        float vals[4] = {kv.x, kv.y, kv.z, kv.w};
        int   msks[4] = {mi.x, mi.y, mi.z, mi.w};

        unsigned int bits = (msks[0] ? 1u : 0u) | (msks[1] ? 2u : 0u) |
                            (msks[2] ? 4u : 0u) | (msks[3] ? 8u : 0u);
        mybits |= bits << (i * 4);

#pragma unroll
        for (int j = 0; j < 4; ++j) {
            float sc = qwv - vals[j];
            sc = fmaxf(sc, 0.01f * sc);
            if (msks[j]) {
                if (sc > m) { s = s * __expf(m - sc) + 1.f; m = sc; }
                else        { s += __expf(sc - m); }
            }
        }
    }
#pragma unroll
    for (int off = 32; off >= 1; off >>= 1) {
        float mo = __shfl_xor(m, off, 64);
        float so = __shfl_xor(s, off, 64);
        float M  = fmaxf(m, mo);
        float sa = (m  == M) ? s  : s  * __expf(m  - M);
        float sb = (mo == M) ? so : so * __expf(mo - M);
        m = M; s = sa + sb;
    }
    const float inv = (s > 0.f) ? 1.f / s : 0.f;
    if (lane == 0) {
        ws[WS_M   + rid] = m;
        ws[WS_INV + rid] = inv;
    }

    // ---- pass 2: exact p, coalesced attn write ----
    float* arow = attn + (size_t)rid * LK;
#pragma unroll
    for (int i = 0; i < 8; ++i) {
        float4 kv = reinterpret_cast<const float4*>(kws)[i * 64 + lane];
        float vals[4] = {kv.x, kv.y, kv.z, kv.w};
        unsigned int bits = (mybits >> (i * 4)) & 0xFu;
        float p[4];
#pragma unroll
        for (int j = 0; j < 4; ++j) {
            float sc = qwv - vals[j];
            sc = fmaxf(sc, 0.01f * sc);
            p[j] = (bits & (1u << j)) ? __expf(sc - m) * inv : 0.f;
        }
        *reinterpret_cast<float4*>(arow + (i * 64 + lane) * 4) =
            make_float4(p[0], p[1], p[2], p[3]);
    }
}

// ---------------------------------------------------------------------------
// B2: PV matmul. p READ from attn (already exact), split to bf16 hi/lo,
// staged in double-buffered fragment-order LDS. ONE barrier per k-step.
// M=64 q-tile, 512 thr (8 waves), wave = 64 q-rows x 64 n-cols.
// ---------------------------------------------------------------------------
__global__ __launch_bounds__(512, 2) void pv_kernel(
        const float* __restrict__ attn,
        const unsigned short* __restrict__ vH,
        const unsigned short* __restrict__ vL,
        float* __restrict__ dst,
        int nks) {
    __shared__ unsigned int pH32[2][1024];
    __shared__ unsigned int pL32[2][1024];

    const int bid = blockIdx.x;
    const int ks  = (nks == 2) ? (bid & 1) : 0;
    const int rst = (nks == 2) ? (bid >> 1) : bid;
    const int b   = rst & 3;
    const int qt  = rst >> 2;              // 0..31
    const int kspan  = LK / nks;
    const int ksteps = kspan >> 5;
    const int kbase  = ks * kspan;
    float* dstk = dst + (size_t)ks * ((size_t)BB * LQ * DV);

    const int t = threadIdx.x;
    const int w = t >> 6, l = t & 63;

    // staging decode: thread t owns LDS u32 words t (rows 0..31) and t+512 (32..63)
    const int m0   = t >> 8;               // 0..1
    const int lp   = (t >> 2) & 63;
    const int jp   = t & 3;
    const int row0 = m0 * 16 + (lp & 15);  // 0..31
    const int kk   = ((lp >> 4) << 3) + (jp << 1);   // even, 0..30
    const int rid0 = b * LQ + qt * 64 + row0;
    const int rid1 = rid0 + 32;

    const float* arow0 = attn + (size_t)rid0 * LK + kbase + kk;
    const float* arow1 = attn + (size_t)rid1 * LK + kbase + kk;

    // B fragment base offsets (u16 units) for chunk 0, per nb
    size_t nbase[4];
#pragma unroll
    for (int nb = 0; nb < 4; ++nb)
        nbase[nb] = (((size_t)(b * 32 + w * 4 + nb)) * 64 + (kbase >> 5)) * 512 + (size_t)l * 8;

    // prologue: B(0), A(0) staged to buf0, A(1) held in regs
    bf16x8 bhC[4], blC[4], bhN[4], blN[4];
#pragma unroll
    for (int nb = 0; nb < 4; ++nb) {
        bhC[nb] = *reinterpret_cast<const bf16x8*>(vH + nbase[nb]);
        blC[nb] = *reinterpret_cast<const bf16x8*>(vL + nbase[nb]);
    }
    {
        float2 a00 = *reinterpret_cast<const float2*>(arow0);
        float2 a01 = *reinterpret_cast<const float2*>(arow1);
        unsigned short h0, lo0, h1, lo1;
        bsplit(a00.x, h0, lo0); bsplit(a00.y, h1, lo1);
        pH32[0][t] = (unsigned int)h0 | ((unsigned int)h1 << 16);
        pL32[0][t] = (unsigned int)lo0 | ((unsigned int)lo1 << 16);
        bsplit(a01.x, h0, lo0); bsplit(a01.y, h1, lo1);
        pH32[0][t + 512] = (unsigned int)h0 | ((unsigned int)h1 << 16);
        pL32[0][t + 512] = (unsigned int)lo0 | ((unsigned int)lo1 << 16);
    }
    const int s1 = (ksteps > 1) ? 1 : 0;
    float2 aC0 = *reinterpret_cast<const float2*>(arow0 + s1 * 32);
    float2 aC1 = *reinterpret_cast<const float2*>(arow1 + s1 * 32);

    f32x4 acc[4][4];
#pragma unroll
    for (int mf = 0; mf < 4; ++mf)
#pragma unroll
        for (int nb = 0; nb < 4; ++nb)
            acc[mf][nb] = (f32x4){0.f, 0.f, 0.f, 0.f};

    __syncthreads();

    for (int s = 0; s < ksteps; ++s) {
        const int buf  = s & 1;
        const int nbuf = buf ^ 1;
        const int sn   = (s + 1 < ksteps) ? s + 1 : s;   // B prefetch
        const int sn2  = (s + 2 < ksteps) ? s + 2 : s;   // A prefetch

        // 1. issue global prefetches (complete long before the barrier)
#pragma unroll
        for (int nb = 0; nb < 4; ++nb) {
            bhN[nb] = *reinterpret_cast<const bf16x8*>(vH + nbase[nb] + (size_t)sn * 512);
            blN[nb] = *reinterpret_cast<const bf16x8*>(vL + nbase[nb] + (size_t)sn * 512);
        }
        float2 aN0 = *reinterpret_cast<const float2*>(arow0 + sn2 * 32);
        float2 aN1 = *reinterpret_cast<const float2*>(arow1 + sn2 * 32);

        // 2. ds_read this step's A fragments from buf
        const bf16x8* pHf = reinterpret_cast<const bf16x8*>(pH32[buf]);
        const bf16x8* pLf = reinterpret_cast<const bf16x8*>(pL32[buf]);
        bf16x8 aH[4], aL[4];
#pragma unroll
        for (int mf = 0; mf < 4; ++mf) {
            aH[mf] = pHf[mf * 64 + l];
            aL[mf] = pLf[mf * 64 + l];
        }

        // 3. stage A(s+1) (regs from last iter) into nbuf — pure VALU+DS-write
        {
            unsigned short h0, lo0, h1, lo1;
            bsplit(aC0.x, h0, lo0); bsplit(aC0.y, h1, lo1);
            pH32[nbuf][t] = (unsigned int)h0 | ((unsigned int)h1 << 16);
            pL32[nbuf][t] = (unsigned int)lo0 | ((unsigned int)lo1 << 16);
            bsplit(aC1.x, h0, lo0); bsplit(aC1.y, h1, lo1);
            pH32[nbuf][t + 512] = (unsigned int)h0 | ((unsigned int)h1 << 16);
            pL32[nbuf][t + 512] = (unsigned int)lo0 | ((unsigned int)lo1 << 16);
        }

        // 4. MFMA cluster
        __builtin_amdgcn_s_setprio(1);
#pragma unroll
        for (int nb = 0; nb < 4; ++nb)
#pragma unroll
            for (int mf = 0; mf < 4; ++mf) {
                acc[mf][nb] = __builtin_amdgcn_mfma_f32_16x16x32_bf16(aH[mf], bhC[nb], acc[mf][nb], 0, 0, 0);
                acc[mf][nb] = __builtin_amdgcn_mfma_f32_16x16x32_bf16(aH[mf], blC[nb], acc[mf][nb], 0, 0, 0);
                acc[mf][nb] = __builtin_amdgcn_mfma_f32_16x16x32_bf16(aL[mf], bhC[nb], acc[mf][nb], 0, 0, 0);
            }
        __builtin_amdgcn_s_setprio(0);

        __syncthreads();   // single barrier per step

#pragma unroll
        for (int nb = 0; nb < 4; ++nb) { bhC[nb] = bhN[nb]; blC[nb] = blN[nb]; }
        aC0 = aN0; aC1 = aN1;
    }

    // ---- epilogue: C layout col = l&15, row = mf*16 + (l>>4)*4 + r ----
    float* obase = dstk + ((size_t)(b * LQ + qt * 64)) * DV + w * 64 + (l & 15);
#pragma unroll
    for (int mf = 0; mf < 4; ++mf)
#pragma unroll
        for (int nb = 0; nb < 4; ++nb)
#pragma unroll
            for (int r = 0; r < 4; ++r)
                obase[(size_t)(mf * 16 + (l >> 4) * 4 + r) * DV + nb * 16] = acc[mf][nb][r];
}

// ---------------------------------------------------------------------------
// Reduce: out = part0 + part1 (float4).
// ---------------------------------------------------------------------------
__global__ __launch_bounds__(256) void reduce_kernel(const float* __restrict__ p0,
                                                     const float* __restrict__ p1,
                                                     float* __restrict__ out) {
    const int n4 = BB * LQ * DV / 4;   // 1048576
    int i = blockIdx.x * 256 + threadIdx.x;
    const float4* a = reinterpret_cast<const float4*>(p0);
    const float4* c = reinterpret_cast<const float4*>(p1);
    float4* o = reinterpret_cast<float4*>(out);
    for (; i < n4; i += 262144) {
        float4 x = a[i], y = c[i];
        o[i] = make_float4(x.x + y.x, x.y + y.y, x.z + y.z, x.w + y.w);
    }
}

// ---------------------------------------------------------------------------
extern "C" void kernel_launch(void* const* d_in, const int* in_sizes, int n_in,
                              void* d_out, int out_size, void* d_ws, size_t ws_size,
                              hipStream_t stream) {
    const float* q    = (const float*)d_in[0];
    const float* k    = (const float*)d_in[1];
    const float* v    = (const float*)d_in[2];
    const int*   mask = (const int*)d_in[3];
    const float* w    = (const float*)d_in[4];

    float* out  = (float*)d_out;                       // [B, LQ, DV]
    float* attn = out + (size_t)BB * LQ * DV;          // [B, LQ, LK]
    float* ws   = (float*)d_ws;

    unsigned short* vH    = (unsigned short*)(ws + WS_V16);
    unsigned short* vL    = vH + (size_t)BB * DV * LK;
    float* part0 = ws + WS_PART;
    float* part1 = part0 + (size_t)BB * LQ * DV;

    const bool split = ws_size >= WS_NEEDED_SPLIT;

    qkw_kernel<<<4096, 256, 0, stream>>>(q, k, w, ws);
    vpack_kernel<<<dim3(64, 4), 256, 0, stream>>>(v, vH, vL);
    rowstat_kernel<<<2048, 256, 0, stream>>>(mask, ws, attn);

    if (split) {
        // bid&7 = (ks, b) -> one (batch, k-half) v-slice per XCD (L2 locality)
        pv_kernel<<<256, 512, 0, stream>>>(attn, vH, vL, part0, 2);
        reduce_kernel<<<1024, 256, 0, stream>>>(part0, part1, out);
    } else {
        pv_kernel<<<128, 512, 0, stream>>>(attn, vH, vL, out, 1);
    }
}